// Round 5
// baseline (689.045 us; speedup 1.0000x reference)
//
#include <hip/hip_runtime.h>

// ---------------- types / helpers ----------------
typedef float f32x4 __attribute__((ext_vector_type(4)));
typedef __bf16 bf16x8 __attribute__((ext_vector_type(8)));
typedef unsigned short ushort_t;
typedef ushort_t us4 __attribute__((ext_vector_type(4)));
typedef ushort_t us8 __attribute__((ext_vector_type(8)));

#define MFMA16(a, b, c) __builtin_amdgcn_mfma_f32_16x16x32_bf16((a), (b), (c), 0, 0, 0)

__device__ __forceinline__ ushort_t f2bf(float f) {
    unsigned int u = __builtin_bit_cast(unsigned int, f);
    u += 0x7fffu + ((u >> 16) & 1u);   // RNE
    return (ushort_t)(u >> 16);
}

__device__ __forceinline__ float gelu_fast(float x) {
    // x * sigmoid(1.5957691216*(x + 0.044715 x^3)) == 0.5x(1+tanh(...)), via exp2
    float x2 = x * x;
    float t = __builtin_fmaf(0.044715f * x2, x, x);
    float e = __builtin_amdgcn_exp2f(t * (-1.5957691216f * 1.44269504f));
    return x * __builtin_amdgcn_rcpf(1.0f + e);
}

// ---------------- problem constants ----------------
#define NWIN_TOT 4096
#define NTOK 98
#define CCH 96
#define QSCALE 0.17677669529663687f  // 1/sqrt(32)

// workspace byte offsets
#define XW_OFF      ((size_t)0)
#define XW_BYTES    ((size_t)NWIN_TOT * NTOK * CCH * 2)          // 77,070,336
#define WQKVP_OFF   (XW_OFF + XW_BYTES + 4096)                   // pad for padded-row overreads
#define WPROJP_OFF  (WQKVP_OFF + (size_t)27648 * 2)
#define WFC1P_OFF   (WPROJP_OFF + (size_t)9216 * 2)
#define WFC2P_OFF   (WFC1P_OFF + (size_t)36864 * 2)
#define BIAS_OFF    (WFC2P_OFF + (size_t)36864 * 2)
#define XO_OFF      (BIAS_OFF + (size_t)28812 * 4 + 256)
// XO: 4096*98*96*2 + pad

// ---------------- K0: weight repack into MFMA B-fragment order + rel-pos bias ----------------
__global__ __launch_bounds__(256) void prep_kernel(
    const float* __restrict__ qkv_w, const float* __restrict__ proj_w,
    const float* __restrict__ fc1_w, const float* __restrict__ fc2_w,
    const float* __restrict__ rpb,
    ushort_t* __restrict__ wqkvP, ushort_t* __restrict__ wprojP,
    ushort_t* __restrict__ wfc1P, ushort_t* __restrict__ wfc2P,
    float* __restrict__ bias)
{
    int i = blockIdx.x * 256 + threadIdx.x;
    if (i < 27648) {  // qkv: f = ((h*3+w)*2+nt)*3+k0
        int f = i >> 9, r = i & 511, lane = r >> 3, m = r & 7;
        int k0 = f % 3, t = f / 3, nt = t % 2, t2 = t / 2, w = t2 % 3, h = t2 / 3;
        int row = k0 * 32 + (lane >> 4) * 8 + m;
        int col = w * 96 + h * 32 + nt * 16 + (lane & 15);
        wqkvP[i] = f2bf(qkv_w[row * 288 + col]);
        return;
    }
    i -= 27648;
    if (i < 9216) {   // proj: f = nt*3+k0
        int f = i >> 9, r = i & 511, lane = r >> 3, m = r & 7;
        int k0 = f % 3, nt = f / 3;
        int row = k0 * 32 + (lane >> 4) * 8 + m;
        int col = nt * 16 + (lane & 15);
        wprojP[i] = f2bf(proj_w[row * 96 + col]);
        return;
    }
    i -= 9216;
    if (i < 36864) {  // fc1: f = nt*3+k0, nt<24
        int f = i >> 9, r = i & 511, lane = r >> 3, m = r & 7;
        int k0 = f % 3, nt = f / 3;
        int row = k0 * 32 + (lane >> 4) * 8 + m;
        int col = nt * 16 + (lane & 15);
        wfc1P[i] = f2bf(fc1_w[row * 384 + col]);
        return;
    }
    i -= 36864;
    if (i < 36864) {  // fc2: f = nt*12+k0, nt<6, k0<12
        int f = i >> 9, r = i & 511, lane = r >> 3, m = r & 7;
        int k0 = f % 12, nt = f / 12;
        int row = k0 * 32 + (lane >> 4) * 8 + m;
        int col = nt * 16 + (lane & 15);
        wfc2P[i] = f2bf(fc2_w[row * 96 + col]);
        return;
    }
    i -= 36864;
    if (i < 28812) {
        int h = i / 9604, rem = i % 9604, r = rem / 98, c = rem % 98;
        int rd = r / 49 - c / 49 + 1;
        int rh = (r % 49) / 7 - (c % 49) / 7 + 6;
        int rw = r % 7 - c % 7 + 6;
        int idx = (rd * 13 + rh) * 13 + rw;
        bias[i] = rpb[idx * 3 + h];
    }
}

// ---------------- K1: LN1 + shift + window partition -> bf16 tokens ----------------
__global__ __launch_bounds__(256) void ln1_window_kernel(
    const float* __restrict__ x, const float* __restrict__ w, const float* __restrict__ b,
    ushort_t* __restrict__ xw)
{
    int token = blockIdx.x * 8 + (threadIdx.x >> 5);
    int lane = threadIdx.x & 31;
    int win = token / 98, n = token - win * 98;
    int bb = win >> 11, wm = win & 2047;
    int id_ = wm >> 8, ih = (wm >> 4) & 15, iw = wm & 15;
    int td = n / 49, r49 = n - td * 49, th = r49 / 7, tw = r49 - th * 7;
    int od = (id_ * 2 + td + 1) & 15;
    int oh = ih * 7 + th + 3; if (oh >= 112) oh -= 112;
    int ow = iw * 7 + tw + 3; if (ow >= 112) ow -= 112;
    const float* xp = x + (((((size_t)(bb << 4) + od) * 112 + oh) * 112) + ow) * 96;
    float v0 = xp[lane], v1 = xp[lane + 32], v2 = xp[lane + 64];
    float s = v0 + v1 + v2, sq = v0 * v0 + v1 * v1 + v2 * v2;
    #pragma unroll
    for (int m = 1; m < 32; m <<= 1) { s += __shfl_xor(s, m, 64); sq += __shfl_xor(sq, m, 64); }
    float mean = s * (1.0f / 96.0f);
    float var = sq * (1.0f / 96.0f) - mean * mean;
    float rs = rsqrtf(var + 1e-5f);
    ushort_t* op = xw + (size_t)token * 96;
    op[lane]      = f2bf((v0 - mean) * rs * w[lane]      + b[lane]);
    op[lane + 32] = f2bf((v1 - mean) * rs * w[lane + 32] + b[lane + 32]);
    op[lane + 64] = f2bf((v2 - mean) * rs * w[lane + 64] + b[lane + 64]);
}

// ---------------- K2: attention core ----------------
// one block (384 thr, 6 waves) per wm; wave = bb*3 + h; zero barriers.
// All 6 waves share the same mask slice (L2/L1 hot); 3 waves share each xw slice (L1).
__global__ __launch_bounds__(384, 4) void attn_core(
    const float* __restrict__ mask, const float* __restrict__ qkv_b,
    const ushort_t* __restrict__ xw, const ushort_t* __restrict__ wqkvP,
    const float* __restrict__ bias, ushort_t* __restrict__ xo)
{
    // per-wave scratch, serially reused: q/k staging (112 rows x stride 36 = 4032 us)
    // then vT (32 rows x stride 136 = 4352 us); P ping-pongs over vT rows 0..15 / 16..31.
    __shared__ ushort_t sc_all[6][4352];   // 52,224 B -> 3 blocks/CU

    const int tid  = threadIdx.x;
    const int lane = tid & 63;
    const int wave = tid >> 6;
    const int l16  = lane & 15, lg = lane >> 4;

    const int wm = blockIdx.x;           // 0..2047
    const int bb = wave / 3, h = wave - bb * 3;
    const int wid = (bb << 11) | wm;

    ushort_t* sc = sc_all[wave];
    const ushort_t* xwg = xw + (size_t)wid * (NTOK * CCH);
    const float* maskw = mask + (size_t)wm * 9604;
    const float* biash = bias + h * 9604;

    bf16x8 qf[7], kf[7], vf[2][4];

    // ---------- stage Q/K/V via serial per-wave LDS reuse ----------
    #pragma unroll
    for (int which = 0; which < 3; ++which) {
        bf16x8 bw[2][3];
        float  bia[2];
        #pragma unroll
        for (int nt = 0; nt < 2; ++nt) {
            bia[nt] = qkv_b[which * 96 + h * 32 + nt * 16 + l16];
            #pragma unroll
            for (int k0 = 0; k0 < 3; ++k0)
                bw[nt][k0] = *(const bf16x8*)(wqkvP + ((((h * 3 + which) * 2 + nt) * 3 + k0) << 9) + lane * 8);
        }
        for (int mt = 0; mt < 7; ++mt) {
            const ushort_t* ap = xwg + (size_t)(mt * 16 + l16) * 96 + lg * 8;
            bf16x8 a0 = *(const bf16x8*)(ap);
            bf16x8 a1 = *(const bf16x8*)(ap + 32);
            bf16x8 a2 = *(const bf16x8*)(ap + 64);
            #pragma unroll
            for (int nt = 0; nt < 2; ++nt) {
                f32x4 acc = {0.f, 0.f, 0.f, 0.f};
                acc = MFMA16(a0, bw[nt][0], acc);
                acc = MFMA16(a1, bw[nt][1], acc);
                acc = MFMA16(a2, bw[nt][2], acc);
                if (which == 2) {
                    us4 pk;
                    #pragma unroll
                    for (int j = 0; j < 4; ++j) pk[j] = f2bf(acc[j] + bia[nt]);
                    *(us4*)(sc + (nt * 16 + l16) * 136 + mt * 16 + lg * 4) = pk;
                } else {
                    float scl = (which == 0) ? QSCALE : 1.0f;
                    #pragma unroll
                    for (int j = 0; j < 4; ++j)
                        sc[(mt * 16 + lg * 4 + j) * 36 + nt * 16 + l16] = f2bf((acc[j] + bia[nt]) * scl);
                }
            }
        }
        if (which == 0) {
            #pragma unroll
            for (int mt = 0; mt < 7; ++mt)
                qf[mt] = *(const bf16x8*)(sc + (mt * 16 + l16) * 36 + lg * 8);
        } else if (which == 1) {
            #pragma unroll
            for (int nt = 0; nt < 7; ++nt)
                kf[nt] = *(const bf16x8*)(sc + (nt * 16 + l16) * 36 + lg * 8);
        } else {
            // zero vT pad cols 112..127 (rows 0..31) -> also zero-pads both P buffers
            us8 z = {0, 0, 0, 0, 0, 0, 0, 0};
            *(us8*)(sc + (lane >> 1) * 136 + 112 + (lane & 1) * 8) = z;
            #pragma unroll
            for (int nt2 = 0; nt2 < 2; ++nt2)
                #pragma unroll
                for (int k0 = 0; k0 < 4; ++k0)
                    vf[nt2][k0] = *(const bf16x8*)(sc + (nt2 * 16 + l16) * 136 + k0 * 32 + lg * 8);
        }
    }

    ushort_t* xog = xo + (size_t)wid * (NTOK * CCH);

    // ---------- attention: 7 M-tiles, all in-wave; P ping-pong across mt ----------
    #pragma unroll
    for (int mt = 0; mt < 7; ++mt) {
        ushort_t* pbuf = sc + (mt & 1) * 2176;   // rows 0..15 / 16..31 of vT region (dead after vf load)
        f32x4 sv[7];
        #pragma unroll
        for (int nt = 0; nt < 7; ++nt) {
            f32x4 z = {0.f, 0.f, 0.f, 0.f};
            sv[nt] = MFMA16(qf[mt], kf[nt], z);
        }
        const int r0 = mt * 16 + lg * 4;
        const bool ctail = (l16 < 2);   // col 96+l16 < 98
        #pragma unroll
        for (int j = 0; j < 4; ++j) {
            int r = r0 + j;
            if (r < 98) {
                const float* bp_ = biash + r * 98;
                const float* mp_ = maskw + r * 98;
                #pragma unroll
                for (int nt = 0; nt < 6; ++nt) {
                    int c = nt * 16 + l16;
                    sv[nt][j] += bp_[c] + mp_[c];
                }
                if (ctail) sv[6][j] += bp_[96 + l16] + mp_[96 + l16];
                else       sv[6][j] = -1e30f;
            } else {
                #pragma unroll
                for (int nt = 0; nt < 7; ++nt) sv[nt][j] = -1e30f;
            }
        }
        // in-register softmax, no max subtraction (|S| bounded << 80)
        f32x4 inv;
        #pragma unroll
        for (int j = 0; j < 4; ++j) {
            float sum = 0.f;
            #pragma unroll
            for (int nt = 0; nt < 7; ++nt) { float e = __expf(sv[nt][j]); sv[nt][j] = e; sum += e; }
            sum += __shfl_xor(sum, 1); sum += __shfl_xor(sum, 2);
            sum += __shfl_xor(sum, 4); sum += __shfl_xor(sum, 8);
            inv[j] = __builtin_amdgcn_rcpf(sum);
        }
        // write P (unnormalized, bf16)
        #pragma unroll
        for (int j = 0; j < 4; ++j)
            #pragma unroll
            for (int nt = 0; nt < 7; ++nt)
                pbuf[(lg * 4 + j) * 136 + nt * 16 + l16] = f2bf(sv[nt][j]);
        bf16x8 pf[4];
        #pragma unroll
        for (int k0 = 0; k0 < 4; ++k0)
            pf[k0] = *(const bf16x8*)(pbuf + l16 * 136 + k0 * 32 + lg * 8);
        #pragma unroll
        for (int nt2 = 0; nt2 < 2; ++nt2) {
            f32x4 acc = {0.f, 0.f, 0.f, 0.f};
            #pragma unroll
            for (int k0 = 0; k0 < 4; ++k0) acc = MFMA16(pf[k0], vf[nt2][k0], acc);
            #pragma unroll
            for (int j = 0; j < 4; ++j) {
                int tok = mt * 16 + lg * 4 + j;
                if (tok < 98)
                    xog[tok * 96 + h * 32 + nt2 * 16 + l16] = f2bf(acc[j] * inv[j]);
            }
        }
    }
}

// ---------------- K2b: proj + shortcut + scatter (no LDS staging; xo rows ARE A-frags) ----------------
__global__ __launch_bounds__(256) void proj_kernel(
    const float* __restrict__ x, const float* __restrict__ proj_b,
    const ushort_t* __restrict__ xo, const ushort_t* __restrict__ wprojP,
    float* __restrict__ dout)
{
    __shared__ int tokbase[112];
    const int tid = threadIdx.x;
    const int lane = tid & 63, wave = tid >> 6;
    const int l16 = lane & 15, lg = lane >> 4;
    const int wid = blockIdx.x;
    const int bb = wid >> 11, wm = wid & 2047;
    const int id_ = wm >> 8, ih = (wm >> 4) & 15, iw = wm & 15;

    if (tid < 98) {
        int td = tid / 49, r49 = tid - td * 49, th = r49 / 7, tw = r49 - th * 7;
        int od = (id_ * 2 + td + 1) & 15;
        int oh = ih * 7 + th + 3; if (oh >= 112) oh -= 112;
        int ow = iw * 7 + tw + 3; if (ow >= 112) ow -= 112;
        tokbase[tid] = ((((bb << 4) + od) * 112 + oh) * 112 + ow) * 96;
    }
    __syncthreads();

    const ushort_t* xog = xo + (size_t)wid * (NTOK * CCH);
    for (int job = wave; job < 42; job += 4) {
        int mt = job / 6, nt = job % 6;
        int cg = nt * 16 + l16;
        f32x4 acc = {0.f, 0.f, 0.f, 0.f};
        #pragma unroll
        for (int k0 = 0; k0 < 3; ++k0) {
            bf16x8 ao = *(const bf16x8*)(xog + (size_t)(mt * 16 + l16) * 96 + k0 * 32 + lg * 8);
            bf16x8 bp = *(const bf16x8*)(wprojP + ((nt * 3 + k0) << 9) + lane * 8);
            acc = MFMA16(ao, bp, acc);
        }
        float pb = proj_b[cg];
        #pragma unroll
        for (int j = 0; j < 4; ++j) {
            int tok = mt * 16 + lg * 4 + j;
            if (tok < 98) {
                int g = tokbase[tok] + cg;
                dout[g] = x[g] + acc[j] + pb;
            }
        }
    }
}

// ---------------- K3: LN2 + MLP + residual (in-place on d_out), 512 threads ----------------
__global__ __launch_bounds__(512, 2) void mlp_kernel(
    float* __restrict__ xres, const float* __restrict__ w2, const float* __restrict__ b2,
    const ushort_t* __restrict__ wfc1P, const float* __restrict__ fc1_b,
    const ushort_t* __restrict__ wfc2P, const float* __restrict__ fc2_b)
{
    __shared__ ushort_t A_ln[64 * 104];
    __shared__ ushort_t h_lds[64 * 392];
    const int tid = threadIdx.x;
    const int lane = tid & 63, wave = tid >> 6;
    const int l16 = lane & 15, lg = lane >> 4;
    const size_t t0 = (size_t)blockIdx.x * 64;

    // LN2 -> bf16 A tile (8 lanes per token, vectorized)
    {
        int t = tid >> 3, sub = tid & 7;
        const float* xp = xres + (t0 + t) * 96;
        f32x4 v[3];
        float s = 0.f, sq = 0.f;
        #pragma unroll
        for (int j4 = 0; j4 < 3; ++j4) {
            v[j4] = *(const f32x4*)(xp + (j4 * 8 + sub) * 4);
            #pragma unroll
            for (int e = 0; e < 4; ++e) { s += v[j4][e]; sq += v[j4][e] * v[j4][e]; }
        }
        s += __shfl_xor(s, 1); s += __shfl_xor(s, 2); s += __shfl_xor(s, 4);
        sq += __shfl_xor(sq, 1); sq += __shfl_xor(sq, 2); sq += __shfl_xor(sq, 4);
        float mean = s * (1.0f / 96.0f);
        float var = sq * (1.0f / 96.0f) - mean * mean;
        float rs = rsqrtf(var + 1e-5f);
        #pragma unroll
        for (int j4 = 0; j4 < 3; ++j4) {
            int c0 = (j4 * 8 + sub) * 4;
            us4 pk;
            #pragma unroll
            for (int e = 0; e < 4; ++e)
                pk[e] = f2bf((v[j4][e] - mean) * rs * w2[c0 + e] + b2[c0 + e]);
            *(us4*)(A_ln + t * 104 + c0) = pk;
        }
    }
    __syncthreads();

    // fc1 + gelu -> h_lds (96 jobs / 8 waves)
    for (int job = wave; job < 96; job += 8) {
        int mt = job / 24, nt = job % 24;
        int n = nt * 16 + l16;
        f32x4 acc = {0.f, 0.f, 0.f, 0.f};
        #pragma unroll
        for (int k0 = 0; k0 < 3; ++k0) {
            bf16x8 a  = *(const bf16x8*)(A_ln + (mt * 16 + l16) * 104 + k0 * 32 + lg * 8);
            bf16x8 bw = *(const bf16x8*)(wfc1P + ((nt * 3 + k0) << 9) + lane * 8);
            acc = MFMA16(a, bw, acc);
        }
        float bv = fc1_b[n];
        #pragma unroll
        for (int j = 0; j < 4; ++j) {
            int tok = mt * 16 + lg * 4 + j;
            h_lds[tok * 392 + n] = f2bf(gelu_fast(acc[j] + bv));
        }
    }
    __syncthreads();

    // fc2 + residual (24 jobs / 8 waves)
    for (int job = wave; job < 24; job += 8) {
        int mt = job / 6, nt = job % 6;
        int c = nt * 16 + l16;
        f32x4 acc = {0.f, 0.f, 0.f, 0.f};
        #pragma unroll
        for (int k0 = 0; k0 < 12; ++k0) {
            bf16x8 a  = *(const bf16x8*)(h_lds + (mt * 16 + l16) * 392 + k0 * 32 + lg * 8);
            bf16x8 bw = *(const bf16x8*)(wfc2P + ((nt * 12 + k0) << 9) + lane * 8);
            acc = MFMA16(a, bw, acc);
        }
        float bv = fc2_b[c];
        #pragma unroll
        for (int j = 0; j < 4; ++j) {
            int tok = mt * 16 + lg * 4 + j;
            size_t g = (t0 + tok) * 96 + c;
            xres[g] = xres[g] + acc[j] + bv;
        }
    }
}

// ---------------- launcher ----------------
extern "C" void kernel_launch(void* const* d_in, const int* in_sizes, int n_in,
                              void* d_out, int out_size, void* d_ws, size_t ws_size,
                              hipStream_t stream) {
    const float* x      = (const float*)d_in[0];
    const float* mask   = (const float*)d_in[1];
    const float* n1w    = (const float*)d_in[2];
    const float* n1b    = (const float*)d_in[3];
    const float* qkv_w  = (const float*)d_in[4];
    const float* qkv_b  = (const float*)d_in[5];
    const float* rpb    = (const float*)d_in[6];
    const float* proj_w = (const float*)d_in[7];
    const float* proj_b = (const float*)d_in[8];
    const float* n2w    = (const float*)d_in[9];
    const float* n2b    = (const float*)d_in[10];
    const float* fc1_w  = (const float*)d_in[11];
    const float* fc1_b  = (const float*)d_in[12];
    const float* fc2_w  = (const float*)d_in[13];
    const float* fc2_b  = (const float*)d_in[14];

    char* ws = (char*)d_ws;
    ushort_t* xw     = (ushort_t*)(ws + XW_OFF);
    ushort_t* wqkvP  = (ushort_t*)(ws + WQKVP_OFF);
    ushort_t* wprojP = (ushort_t*)(ws + WPROJP_OFF);
    ushort_t* wfc1P  = (ushort_t*)(ws + WFC1P_OFF);
    ushort_t* wfc2P  = (ushort_t*)(ws + WFC2P_OFF);
    float*    biasp  = (float*)(ws + BIAS_OFF);
    ushort_t* xo     = (ushort_t*)(ws + XO_OFF);
    float*    dout   = (float*)d_out;

    prep_kernel<<<545, 256, 0, stream>>>(qkv_w, proj_w, fc1_w, fc2_w, rpb,
                                         wqkvP, wprojP, wfc1P, wfc2P, biasp);
    ln1_window_kernel<<<50176, 256, 0, stream>>>(x, n1w, n1b, xw);
    attn_core<<<2048, 384, 0, stream>>>(mask, qkv_b, xw, wqkvP, biasp, xo);
    proj_kernel<<<4096, 256, 0, stream>>>(x, proj_b, xo, wprojP, dout);
    mlp_kernel<<<6272, 512, 0, stream>>>(dout, n2w, n2b, wfc1P, fc1_b, wfc2P, fc2_b);
}

// Round 6
// 661.563 us; speedup vs baseline: 1.0415x; 1.0415x over previous
//
#include <hip/hip_runtime.h>

// ---------------- types / helpers ----------------
typedef float f32x4 __attribute__((ext_vector_type(4)));
typedef __bf16 bf16x8 __attribute__((ext_vector_type(8)));
typedef unsigned short ushort_t;
typedef ushort_t us4 __attribute__((ext_vector_type(4)));
typedef ushort_t us8 __attribute__((ext_vector_type(8)));

#define MFMA16(a, b, c) __builtin_amdgcn_mfma_f32_16x16x32_bf16((a), (b), (c), 0, 0, 0)

__device__ __forceinline__ ushort_t f2bf(float f) {
    unsigned int u = __builtin_bit_cast(unsigned int, f);
    u += 0x7fffu + ((u >> 16) & 1u);   // RNE
    return (ushort_t)(u >> 16);
}
__device__ __forceinline__ float bf2f(ushort_t u) {
    return __builtin_bit_cast(float, (unsigned int)u << 16);
}

__device__ __forceinline__ float gelu_fast(float x) {
    float x2 = x * x;
    float t = __builtin_fmaf(0.044715f * x2, x, x);
    float e = __builtin_amdgcn_exp2f(t * (-1.5957691216f * 1.44269504f));
    return x * __builtin_amdgcn_rcpf(1.0f + e);
}

// ---------------- problem constants ----------------
#define NWIN_TOT 4096
#define NTOK 98
#define CCH 96
#define QSCALE 0.17677669529663687f  // 1/sqrt(32)

// workspace byte offsets
#define XW_OFF      ((size_t)0)
#define XW_BYTES    ((size_t)NWIN_TOT * NTOK * CCH * 2)          // 77,070,336
#define WQKVP_OFF   (XW_OFF + XW_BYTES + 4096)
#define WPROJP_OFF  (WQKVP_OFF + (size_t)27648 * 2)
#define WFC1P_OFF   (WPROJP_OFF + (size_t)9216 * 2)
#define WFC2P_OFF   (WFC1P_OFF + (size_t)36864 * 2)
#define BIAS_OFF    (WFC2P_OFF + (size_t)36864 * 2)               // 28812 f32
#define MASKB_OFF   (BIAS_OFF + (size_t)28812 * 4 + 256)          // bf16 mask 2048*9604
#define XO_OFF      (MASKB_OFF + (size_t)2048 * 9604 * 2 + 256)
// XO: [wid][h][112][32] bf16 = 4096*3*112*32*2 = 88,080,384 B

// ---------------- K0: weight repack into MFMA B-fragment order + rel-pos bias ----------------
__global__ __launch_bounds__(256) void prep_kernel(
    const float* __restrict__ qkv_w, const float* __restrict__ proj_w,
    const float* __restrict__ fc1_w, const float* __restrict__ fc2_w,
    const float* __restrict__ rpb,
    ushort_t* __restrict__ wqkvP, ushort_t* __restrict__ wprojP,
    ushort_t* __restrict__ wfc1P, ushort_t* __restrict__ wfc2P,
    float* __restrict__ bias)
{
    int i = blockIdx.x * 256 + threadIdx.x;
    if (i < 27648) {  // qkv: f = ((h*3+w)*2+nt)*3+k0
        int f = i >> 9, r = i & 511, lane = r >> 3, m = r & 7;
        int k0 = f % 3, t = f / 3, nt = t % 2, t2 = t / 2, w = t2 % 3, h = t2 / 3;
        int row = k0 * 32 + (lane >> 4) * 8 + m;
        int col = w * 96 + h * 32 + nt * 16 + (lane & 15);
        wqkvP[i] = f2bf(qkv_w[row * 288 + col]);
        return;
    }
    i -= 27648;
    if (i < 9216) {   // proj: f = nt*3+k0
        int f = i >> 9, r = i & 511, lane = r >> 3, m = r & 7;
        int k0 = f % 3, nt = f / 3;
        int row = k0 * 32 + (lane >> 4) * 8 + m;
        int col = nt * 16 + (lane & 15);
        wprojP[i] = f2bf(proj_w[row * 96 + col]);
        return;
    }
    i -= 9216;
    if (i < 36864) {  // fc1
        int f = i >> 9, r = i & 511, lane = r >> 3, m = r & 7;
        int k0 = f % 3, nt = f / 3;
        int row = k0 * 32 + (lane >> 4) * 8 + m;
        int col = nt * 16 + (lane & 15);
        wfc1P[i] = f2bf(fc1_w[row * 384 + col]);
        return;
    }
    i -= 36864;
    if (i < 36864) {  // fc2
        int f = i >> 9, r = i & 511, lane = r >> 3, m = r & 7;
        int k0 = f % 12, nt = f / 12;
        int row = k0 * 32 + (lane >> 4) * 8 + m;
        int col = nt * 16 + (lane & 15);
        wfc2P[i] = f2bf(fc2_w[row * 96 + col]);
        return;
    }
    i -= 36864;
    if (i < 28812) {
        int h = i / 9604, rem = i % 9604, r = rem / 98, c = rem % 98;
        int rd = r / 49 - c / 49 + 1;
        int rh = (r % 49) / 7 - (c % 49) / 7 + 6;
        int rw = r % 7 - c % 7 + 6;
        int idx = (rd * 13 + rh) * 13 + rw;
        bias[i] = rpb[idx * 3 + h];
    }
}

// ---------------- K0b: mask fp32 -> bf16 ----------------
__global__ __launch_bounds__(256) void maskconv_kernel(
    const float* __restrict__ m, ushort_t* __restrict__ mb)
{
    size_t i = (size_t)blockIdx.x * 256 + threadIdx.x;   // x4 elements
    f32x4 v = *(const f32x4*)(m + i * 4);
    us4 o;
    #pragma unroll
    for (int e = 0; e < 4; ++e) o[e] = f2bf(v[e]);
    *(us4*)(mb + i * 4) = o;
}

// ---------------- K1: LN1 + shift + window partition -> bf16 tokens ----------------
__global__ __launch_bounds__(256) void ln1_window_kernel(
    const float* __restrict__ x, const float* __restrict__ w, const float* __restrict__ b,
    ushort_t* __restrict__ xw)
{
    int token = blockIdx.x * 8 + (threadIdx.x >> 5);
    int lane = threadIdx.x & 31;
    int win = token / 98, n = token - win * 98;
    int bb = win >> 11, wm = win & 2047;
    int id_ = wm >> 8, ih = (wm >> 4) & 15, iw = wm & 15;
    int td = n / 49, r49 = n - td * 49, th = r49 / 7, tw = r49 - th * 7;
    int od = (id_ * 2 + td + 1) & 15;
    int oh = ih * 7 + th + 3; if (oh >= 112) oh -= 112;
    int ow = iw * 7 + tw + 3; if (ow >= 112) ow -= 112;
    const float* xp = x + (((((size_t)(bb << 4) + od) * 112 + oh) * 112) + ow) * 96;
    float v0 = xp[lane], v1 = xp[lane + 32], v2 = xp[lane + 64];
    float s = v0 + v1 + v2, sq = v0 * v0 + v1 * v1 + v2 * v2;
    #pragma unroll
    for (int m = 1; m < 32; m <<= 1) { s += __shfl_xor(s, m, 64); sq += __shfl_xor(sq, m, 64); }
    float mean = s * (1.0f / 96.0f);
    float var = sq * (1.0f / 96.0f) - mean * mean;
    float rs = rsqrtf(var + 1e-5f);
    ushort_t* op = xw + (size_t)token * 96;
    op[lane]      = f2bf((v0 - mean) * rs * w[lane]      + b[lane]);
    op[lane + 32] = f2bf((v1 - mean) * rs * w[lane + 32] + b[lane + 32]);
    op[lane + 64] = f2bf((v2 - mean) * rs * w[lane + 64] + b[lane + 64]);
}

// ---------------- K2: attention core, one wave = one (window, head), ZERO barriers ----------------
__global__ __launch_bounds__(256, 4) void attn_core(
    const ushort_t* __restrict__ maskb, const float* __restrict__ qkv_b,
    const ushort_t* __restrict__ xw, const ushort_t* __restrict__ wqkvP,
    const float* __restrict__ bias, ushort_t* __restrict__ xo)
{
    // per-wave scratch: q/k staging (112 x stride36 = 4032 us), then vT (32 x stride136 = 4352 us);
    // P ping-pongs over vT rows 0..15 / 16..31 (dead after vf regs loaded).
    __shared__ ushort_t sc_all[4][4352];   // 34,816 B -> 4 blocks/CU

    const int tid  = threadIdx.x;
    const int lane = tid & 63;
    const int wave = tid >> 6;
    const int l16  = lane & 15, lg = lane >> 4;

    // chunked XCD swizzle: adjacent b2 are 8 blocks apart -> near-simultaneous, same XCD;
    // the 6 jobs of one wm sit in 2 adjacent b2 blocks -> mask slice shared in L2.
    int b  = blockIdx.x;                 // 0..3071
    int b2 = (b & 7) * 384 + (b >> 3);
    int job = b2 * 4 + wave;             // 0..12287 = wm*6 + bb*3 + h
    int wm = job / 6, r6 = job - wm * 6;
    int bb = r6 / 3, h = r6 - bb * 3;
    int wid = (bb << 11) | wm;

    ushort_t* sc = sc_all[wave];
    const ushort_t* xwg = xw + (size_t)wid * (NTOK * CCH);
    const ushort_t* maskw = maskb + (size_t)wm * 9604;
    const float* biash = bias + h * 9604;

    bf16x8 qf[7], kf[7], vf[2][4];

    // ---------- stage Q/K/V via serial per-wave LDS reuse ----------
    #pragma unroll
    for (int which = 0; which < 3; ++which) {
        bf16x8 bw[2][3];
        float  bia[2];
        #pragma unroll
        for (int nt = 0; nt < 2; ++nt) {
            bia[nt] = qkv_b[which * 96 + h * 32 + nt * 16 + l16];
            #pragma unroll
            for (int k0 = 0; k0 < 3; ++k0)
                bw[nt][k0] = *(const bf16x8*)(wqkvP + ((((h * 3 + which) * 2 + nt) * 3 + k0) << 9) + lane * 8);
        }
        for (int mt = 0; mt < 7; ++mt) {
            const ushort_t* ap = xwg + (size_t)(mt * 16 + l16) * 96 + lg * 8;
            bf16x8 a0 = *(const bf16x8*)(ap);
            bf16x8 a1 = *(const bf16x8*)(ap + 32);
            bf16x8 a2 = *(const bf16x8*)(ap + 64);
            #pragma unroll
            for (int nt = 0; nt < 2; ++nt) {
                f32x4 acc = {0.f, 0.f, 0.f, 0.f};
                acc = MFMA16(a0, bw[nt][0], acc);
                acc = MFMA16(a1, bw[nt][1], acc);
                acc = MFMA16(a2, bw[nt][2], acc);
                if (which == 2) {
                    us4 pk;
                    #pragma unroll
                    for (int j = 0; j < 4; ++j) pk[j] = f2bf(acc[j] + bia[nt]);
                    *(us4*)(sc + (nt * 16 + l16) * 136 + mt * 16 + lg * 4) = pk;
                } else {
                    float scl = (which == 0) ? QSCALE : 1.0f;
                    #pragma unroll
                    for (int j = 0; j < 4; ++j)
                        sc[(mt * 16 + lg * 4 + j) * 36 + nt * 16 + l16] = f2bf((acc[j] + bia[nt]) * scl);
                }
            }
        }
        if (which == 0) {
            #pragma unroll
            for (int mt = 0; mt < 7; ++mt)
                qf[mt] = *(const bf16x8*)(sc + (mt * 16 + l16) * 36 + lg * 8);
        } else if (which == 1) {
            #pragma unroll
            for (int nt = 0; nt < 7; ++nt)
                kf[nt] = *(const bf16x8*)(sc + (nt * 16 + l16) * 36 + lg * 8);
        } else {
            // zero vT pad cols 112..127 (rows 0..31) -> also zero-pads both P buffers
            us8 z = {0, 0, 0, 0, 0, 0, 0, 0};
            *(us8*)(sc + (lane >> 1) * 136 + 112 + (lane & 1) * 8) = z;
            #pragma unroll
            for (int nt2 = 0; nt2 < 2; ++nt2)
                #pragma unroll
                for (int k0 = 0; k0 < 4; ++k0)
                    vf[nt2][k0] = *(const bf16x8*)(sc + (nt2 * 16 + l16) * 136 + k0 * 32 + lg * 8);
        }
    }

    // xo: [wid][h][tok(112)][32] -> each wave owns a contiguous 7KB region, full-line writes
    ushort_t* xog = xo + ((size_t)wid * 3 + h) * (112 * 32);

    // ---------- attention: 7 M-tiles, all in-wave; P ping-pong across mt ----------
    #pragma unroll
    for (int mt = 0; mt < 7; ++mt) {
        ushort_t* pbuf = sc + (mt & 1) * 2176;
        f32x4 sv[7];
        #pragma unroll
        for (int nt = 0; nt < 7; ++nt) {
            f32x4 z = {0.f, 0.f, 0.f, 0.f};
            sv[nt] = MFMA16(qf[mt], kf[nt], z);
        }
        const int r0 = mt * 16 + lg * 4;
        const bool ctail = (l16 < 2);   // col 96+l16 < 98
        #pragma unroll
        for (int j = 0; j < 4; ++j) {
            int r = r0 + j;
            if (r < 98) {
                const float* bp_ = biash + r * 98;
                const ushort_t* mp_ = maskw + r * 98;
                #pragma unroll
                for (int nt = 0; nt < 6; ++nt) {
                    int c = nt * 16 + l16;
                    sv[nt][j] += bp_[c] + bf2f(mp_[c]);
                }
                if (ctail) sv[6][j] += bp_[96 + l16] + bf2f(mp_[96 + l16]);
                else       sv[6][j] = -1e30f;
            } else {
                #pragma unroll
                for (int nt = 0; nt < 7; ++nt) sv[nt][j] = -1e30f;
            }
        }
        // in-register softmax, no max subtraction (|S| bounded << 80)
        f32x4 inv;
        #pragma unroll
        for (int j = 0; j < 4; ++j) {
            float sum = 0.f;
            #pragma unroll
            for (int nt = 0; nt < 7; ++nt) { float e = __expf(sv[nt][j]); sv[nt][j] = e; sum += e; }
            sum += __shfl_xor(sum, 1); sum += __shfl_xor(sum, 2);
            sum += __shfl_xor(sum, 4); sum += __shfl_xor(sum, 8);
            inv[j] = __builtin_amdgcn_rcpf(sum);
        }
        #pragma unroll
        for (int j = 0; j < 4; ++j)
            #pragma unroll
            for (int nt = 0; nt < 7; ++nt)
                pbuf[(lg * 4 + j) * 136 + nt * 16 + l16] = f2bf(sv[nt][j]);
        bf16x8 pf[4];
        #pragma unroll
        for (int k0 = 0; k0 < 4; ++k0)
            pf[k0] = *(const bf16x8*)(pbuf + l16 * 136 + k0 * 32 + lg * 8);
        #pragma unroll
        for (int nt2 = 0; nt2 < 2; ++nt2) {
            f32x4 acc = {0.f, 0.f, 0.f, 0.f};
            #pragma unroll
            for (int k0 = 0; k0 < 4; ++k0) acc = MFMA16(pf[k0], vf[nt2][k0], acc);
            #pragma unroll
            for (int j = 0; j < 4; ++j) {
                int tok = mt * 16 + lg * 4 + j;
                if (tok < 98)
                    xog[tok * 32 + nt2 * 16 + l16] = f2bf(acc[j] * inv[j]);
            }
        }
    }
}

// ---------------- K2b: proj + shortcut + scatter ----------------
__global__ __launch_bounds__(256) void proj_kernel(
    const float* __restrict__ x, const float* __restrict__ proj_b,
    const ushort_t* __restrict__ xo, const ushort_t* __restrict__ wprojP,
    float* __restrict__ dout)
{
    __shared__ int tokbase[112];
    const int tid = threadIdx.x;
    const int lane = tid & 63, wave = tid >> 6;
    const int l16 = lane & 15, lg = lane >> 4;
    const int wid = blockIdx.x;
    const int bb = wid >> 11, wm = wid & 2047;
    const int id_ = wm >> 8, ih = (wm >> 4) & 15, iw = wm & 15;

    if (tid < 98) {
        int td = tid / 49, r49 = tid - td * 49, th = r49 / 7, tw = r49 - th * 7;
        int od = (id_ * 2 + td + 1) & 15;
        int oh = ih * 7 + th + 3; if (oh >= 112) oh -= 112;
        int ow = iw * 7 + tw + 3; if (ow >= 112) ow -= 112;
        tokbase[tid] = ((((bb << 4) + od) * 112 + oh) * 112 + ow) * 96;
    }
    __syncthreads();

    const ushort_t* xog = xo + (size_t)wid * (3 * 112 * 32);
    for (int job = wave; job < 42; job += 4) {
        int mt = job / 6, nt = job % 6;
        int cg = nt * 16 + l16;
        f32x4 acc = {0.f, 0.f, 0.f, 0.f};
        #pragma unroll
        for (int k0 = 0; k0 < 3; ++k0) {
            bf16x8 ao = *(const bf16x8*)(xog + (k0 * 112 + mt * 16 + l16) * 32 + lg * 8);
            bf16x8 bp = *(const bf16x8*)(wprojP + ((nt * 3 + k0) << 9) + lane * 8);
            acc = MFMA16(ao, bp, acc);
        }
        float pb = proj_b[cg];
        #pragma unroll
        for (int j = 0; j < 4; ++j) {
            int tok = mt * 16 + lg * 4 + j;
            if (tok < 98) {
                int g = tokbase[tok] + cg;
                dout[g] = x[g] + acc[j] + pb;
            }
        }
    }
}

// ---------------- K3: LN2 + MLP + residual (in-place on d_out), 512 threads ----------------
__global__ __launch_bounds__(512, 2) void mlp_kernel(
    float* __restrict__ xres, const float* __restrict__ w2, const float* __restrict__ b2,
    const ushort_t* __restrict__ wfc1P, const float* __restrict__ fc1_b,
    const ushort_t* __restrict__ wfc2P, const float* __restrict__ fc2_b)
{
    __shared__ ushort_t A_ln[64 * 104];
    __shared__ ushort_t h_lds[64 * 392];
    const int tid = threadIdx.x;
    const int lane = tid & 63, wave = tid >> 6;
    const int l16 = lane & 15, lg = lane >> 4;
    const size_t t0 = (size_t)blockIdx.x * 64;

    {
        int t = tid >> 3, sub = tid & 7;
        const float* xp = xres + (t0 + t) * 96;
        f32x4 v[3];
        float s = 0.f, sq = 0.f;
        #pragma unroll
        for (int j4 = 0; j4 < 3; ++j4) {
            v[j4] = *(const f32x4*)(xp + (j4 * 8 + sub) * 4);
            #pragma unroll
            for (int e = 0; e < 4; ++e) { s += v[j4][e]; sq += v[j4][e] * v[j4][e]; }
        }
        s += __shfl_xor(s, 1); s += __shfl_xor(s, 2); s += __shfl_xor(s, 4);
        sq += __shfl_xor(sq, 1); sq += __shfl_xor(sq, 2); sq += __shfl_xor(sq, 4);
        float mean = s * (1.0f / 96.0f);
        float var = sq * (1.0f / 96.0f) - mean * mean;
        float rs = rsqrtf(var + 1e-5f);
        #pragma unroll
        for (int j4 = 0; j4 < 3; ++j4) {
            int c0 = (j4 * 8 + sub) * 4;
            us4 pk;
            #pragma unroll
            for (int e = 0; e < 4; ++e)
                pk[e] = f2bf((v[j4][e] - mean) * rs * w2[c0 + e] + b2[c0 + e]);
            *(us4*)(A_ln + t * 104 + c0) = pk;
        }
    }
    __syncthreads();

    for (int job = wave; job < 96; job += 8) {
        int mt = job / 24, nt = job % 24;
        int n = nt * 16 + l16;
        f32x4 acc = {0.f, 0.f, 0.f, 0.f};
        #pragma unroll
        for (int k0 = 0; k0 < 3; ++k0) {
            bf16x8 a  = *(const bf16x8*)(A_ln + (mt * 16 + l16) * 104 + k0 * 32 + lg * 8);
            bf16x8 bw = *(const bf16x8*)(wfc1P + ((nt * 3 + k0) << 9) + lane * 8);
            acc = MFMA16(a, bw, acc);
        }
        float bv = fc1_b[n];
        #pragma unroll
        for (int j = 0; j < 4; ++j) {
            int tok = mt * 16 + lg * 4 + j;
            h_lds[tok * 392 + n] = f2bf(gelu_fast(acc[j] + bv));
        }
    }
    __syncthreads();

    for (int job = wave; job < 24; job += 8) {
        int mt = job / 6, nt = job % 6;
        int c = nt * 16 + l16;
        f32x4 acc = {0.f, 0.f, 0.f, 0.f};
        #pragma unroll
        for (int k0 = 0; k0 < 12; ++k0) {
            bf16x8 a  = *(const bf16x8*)(h_lds + (mt * 16 + l16) * 392 + k0 * 32 + lg * 8);
            bf16x8 bw = *(const bf16x8*)(wfc2P + ((nt * 12 + k0) << 9) + lane * 8);
            acc = MFMA16(a, bw, acc);
        }
        float bv = fc2_b[c];
        #pragma unroll
        for (int j = 0; j < 4; ++j) {
            int tok = mt * 16 + lg * 4 + j;
            size_t g = (t0 + tok) * 96 + c;
            xres[g] = xres[g] + acc[j] + bv;
        }
    }
}

// ---------------- launcher ----------------
extern "C" void kernel_launch(void* const* d_in, const int* in_sizes, int n_in,
                              void* d_out, int out_size, void* d_ws, size_t ws_size,
                              hipStream_t stream) {
    const float* x      = (const float*)d_in[0];
    const float* mask   = (const float*)d_in[1];
    const float* n1w    = (const float*)d_in[2];
    const float* n1b    = (const float*)d_in[3];
    const float* qkv_w  = (const float*)d_in[4];
    const float* qkv_b  = (const float*)d_in[5];
    const float* rpb    = (const float*)d_in[6];
    const float* proj_w = (const float*)d_in[7];
    const float* proj_b = (const float*)d_in[8];
    const float* n2w    = (const float*)d_in[9];
    const float* n2b    = (const float*)d_in[10];
    const float* fc1_w  = (const float*)d_in[11];
    const float* fc1_b  = (const float*)d_in[12];
    const float* fc2_w  = (const float*)d_in[13];
    const float* fc2_b  = (const float*)d_in[14];

    char* ws = (char*)d_ws;
    ushort_t* xw     = (ushort_t*)(ws + XW_OFF);
    ushort_t* wqkvP  = (ushort_t*)(ws + WQKVP_OFF);
    ushort_t* wprojP = (ushort_t*)(ws + WPROJP_OFF);
    ushort_t* wfc1P  = (ushort_t*)(ws + WFC1P_OFF);
    ushort_t* wfc2P  = (ushort_t*)(ws + WFC2P_OFF);
    float*    biasp  = (float*)(ws + BIAS_OFF);
    ushort_t* maskb  = (ushort_t*)(ws + MASKB_OFF);
    ushort_t* xo     = (ushort_t*)(ws + XO_OFF);
    float*    dout   = (float*)d_out;

    prep_kernel<<<545, 256, 0, stream>>>(qkv_w, proj_w, fc1_w, fc2_w, rpb,
                                         wqkvP, wprojP, wfc1P, wfc2P, biasp);
    maskconv_kernel<<<19208, 256, 0, stream>>>(mask, maskb);
    ln1_window_kernel<<<50176, 256, 0, stream>>>(x, n1w, n1b, xw);
    attn_core<<<3072, 256, 0, stream>>>(maskb, qkv_b, xw, wqkvP, biasp, xo);
    proj_kernel<<<4096, 256, 0, stream>>>(x, proj_b, xo, wprojP, dout);
    mlp_kernel<<<6272, 512, 0, stream>>>(dout, n2w, n2b, wfc1P, fc1_b, wfc2P, fc2_b);
}